// Round 6
// baseline (520.682 us; speedup 1.0000x reference)
//
#include <hip/hip_runtime.h>
#include <stdint.h>

typedef short bf16x8 __attribute__((ext_vector_type(8)));
typedef float f32x4 __attribute__((ext_vector_type(4)));
typedef unsigned short u16x4 __attribute__((ext_vector_type(4)));

__device__ __forceinline__ unsigned short f2b(float f) {
  union { float f; unsigned u; } v; v.f = f;
  unsigned r = v.u + 0x7fffu + ((v.u >> 16) & 1u);
  return (unsigned short)(r >> 16);
}
__device__ __forceinline__ float fsigm(float x) { return 1.f / (1.f + __expf(-x)); }
__device__ __forceinline__ float ftanh(float x) {
  float t = __expf(-2.f * fabsf(x));
  float r = (1.f - t) / (1.f + t);
  return copysignf(r, x);
}

// ---------------- fused transpose+convert: f32[R][C] -> bf16 out[C][R], 12 matrices ----------------
struct TD { const float* in; unsigned short* out; int R, C; };
struct TDs { TD d[12]; };

__global__ __launch_bounds__(256) void tconv_all(TDs ds) {
  TD t = ds.d[blockIdx.z];
  int c0 = blockIdx.x * 32, r0 = blockIdx.y * 32;
  if (c0 >= t.C || r0 >= t.R) return;
  __shared__ float tl[32][33];
  int tx = threadIdx.x & 31, ty = threadIdx.x >> 5;  // 32 x 8
  #pragma unroll
  for (int i = 0; i < 32; i += 8) {
    int r = r0 + ty + i, c = c0 + tx;
    tl[ty + i][tx] = (r < t.R && c < t.C) ? t.in[(size_t)r * t.C + c] : 0.f;
  }
  __syncthreads();
  #pragma unroll
  for (int i = 0; i < 32; i += 8) {
    int c = c0 + ty + i, r = r0 + tx;
    if (c < t.C && r < t.R) t.out[(size_t)c * t.R + r] = f2b(tl[tx][ty + i]);
  }
}

// ---------------- f32 -> bf16 flat convert ----------------
__global__ __launch_bounds__(256) void conv_k(const float* __restrict__ in,
                                              unsigned short* __restrict__ out, int n) {
  int i = (blockIdx.x * 256 + threadIdx.x) * 8;
  if (i >= n) return;
  float4 a = *(const float4*)(in + i);
  float4 b = *(const float4*)(in + i + 4);
  bf16x8 v;
  v[0] = (short)f2b(a.x); v[1] = (short)f2b(a.y); v[2] = (short)f2b(a.z); v[3] = (short)f2b(a.w);
  v[4] = (short)f2b(b.x); v[5] = (short)f2b(b.y); v[6] = (short)f2b(b.z); v[7] = (short)f2b(b.w);
  *(bf16x8*)(out + i) = v;
}

// ---------------- generic MFMA GEMM: C = act(A[M,K] @ BT[N,K]^T + bias) ----------------
template <int ACT, bool OBF16>
__global__ __launch_bounds__(256) void gemm_k(const unsigned short* __restrict__ A,
                                              const unsigned short* __restrict__ BT,
                                              const float* __restrict__ bias,
                                              void* __restrict__ Cp,
                                              int M, int N, int K, int ldC) {
  __shared__ unsigned short As[64][40];
  __shared__ unsigned short Bs[64][40];
  const int tid = threadIdx.x;
  const int n0 = blockIdx.x * 64;
  const int m0 = blockIdx.y * 64;
  const int wid = tid >> 6, lane = tid & 63;
  const int wm = (wid >> 1) * 32, wn = (wid & 1) * 32;
  const int lr = lane & 15, lk = lane >> 4;
  const int sr = tid >> 2, sc = (tid & 3) * 8;

  f32x4 acc[2][2] = {};

  for (int k0 = 0; k0 < K; k0 += 32) {
    *(bf16x8*)&As[sr][sc] = *(const bf16x8*)(A + (size_t)(m0 + sr) * K + k0 + sc);
    {
      int n = n0 + sr;
      bf16x8 v = {};
      if (n < N) v = *(const bf16x8*)(BT + (size_t)n * K + k0 + sc);
      *(bf16x8*)&Bs[sr][sc] = v;
    }
    __syncthreads();
    bf16x8 af[2], bfr[2];
    #pragma unroll
    for (int mi = 0; mi < 2; mi++) af[mi] = *(const bf16x8*)&As[wm + mi * 16 + lr][lk * 8];
    #pragma unroll
    for (int ni = 0; ni < 2; ni++) bfr[ni] = *(const bf16x8*)&Bs[wn + ni * 16 + lr][lk * 8];
    #pragma unroll
    for (int mi = 0; mi < 2; mi++)
      #pragma unroll
      for (int ni = 0; ni < 2; ni++)
        acc[mi][ni] = __builtin_amdgcn_mfma_f32_16x16x32_bf16(af[mi], bfr[ni], acc[mi][ni], 0, 0, 0);
    __syncthreads();
  }

  #pragma unroll
  for (int mi = 0; mi < 2; mi++)
    #pragma unroll
    for (int ni = 0; ni < 2; ni++) {
      int col = n0 + wn + ni * 16 + lr;
      if (col >= N) continue;
      float bv = bias[col];
      #pragma unroll
      for (int r = 0; r < 4; r++) {
        int row = m0 + wm + mi * 16 + lk * 4 + r;
        float v = acc[mi][ni][r] + bv;
        if (ACT == 1) v = fmaxf(v, 0.f);
        if (OBF16) ((unsigned short*)Cp)[(size_t)row * ldC + col] = f2b(v);
        else       ((float*)Cp)[(size_t)row * ldC + col] = v;
      }
    }
}

// ---------------- fused LSTM scan over 16 steps (1024 threads, 16 waves) ----------------
__global__ __launch_bounds__(1024) void lstm_k(const float* __restrict__ c0,
                                               const unsigned short* __restrict__ whhT,  // [512][128]
                                               const float* __restrict__ w_ih,           // [16][512]
                                               const float* __restrict__ b_ih,
                                               const float* __restrict__ b_hh,
                                               unsigned short* __restrict__ h_all) {     // [8192][16][128]
  __shared__ float G[32][516];
  __shared__ float cst[32][128];
  __shared__ unsigned short hst[32][136];
  const int tid = threadIdx.x, lane = tid & 63, wid = tid >> 6;  // wid 0..15
  const int r0 = blockIdx.x * 32;
  const int lr = lane & 15, lk = lane >> 4;

  bf16x8 wv[2][4];
  #pragma unroll
  for (int nj = 0; nj < 2; nj++)
    #pragma unroll
    for (int ks = 0; ks < 4; ks++)
      wv[nj][ks] = *(const bf16x8*)(whhT + (size_t)(wid * 32 + nj * 16 + lr) * 128 + ks * 32 + lk * 8);

  const int j = tid & 127;
  const int rb = tid >> 7;  // 0..7
  const float bs0 = b_ih[j]       + b_hh[j];
  const float bs1 = b_ih[j + 128] + b_hh[j + 128];
  const float bs2 = b_ih[j + 256] + b_hh[j + 256];
  const float bs3 = b_ih[j + 384] + b_hh[j + 384];

  {
    int r = tid >> 5, j4 = (tid & 31) * 4;
    float4 c4 = *(const float4*)(c0 + (size_t)(r0 + r) * 128 + j4);
    *(f32x4*)&cst[r][j4] = f32x4{c4.x, c4.y, c4.z, c4.w};
    u16x4 h4;
    h4[0] = f2b(ftanh(c4.x)); h4[1] = f2b(ftanh(c4.y));
    h4[2] = f2b(ftanh(c4.z)); h4[3] = f2b(ftanh(c4.w));
    *(u16x4*)&hst[r][j4] = h4;
  }
  __syncthreads();

  for (int a = 0; a < 16; a++) {
    f32x4 acc[2][2] = {};
    #pragma unroll
    for (int ks = 0; ks < 4; ks++) {
      bf16x8 af0 = *(const bf16x8*)&hst[lr][ks * 32 + lk * 8];
      bf16x8 af1 = *(const bf16x8*)&hst[16 + lr][ks * 32 + lk * 8];
      #pragma unroll
      for (int nj = 0; nj < 2; nj++) {
        acc[0][nj] = __builtin_amdgcn_mfma_f32_16x16x32_bf16(af0, wv[nj][ks], acc[0][nj], 0, 0, 0);
        acc[1][nj] = __builtin_amdgcn_mfma_f32_16x16x32_bf16(af1, wv[nj][ks], acc[1][nj], 0, 0, 0);
      }
    }
    #pragma unroll
    for (int mi = 0; mi < 2; mi++)
      #pragma unroll
      for (int nj = 0; nj < 2; nj++)
        #pragma unroll
        for (int rr = 0; rr < 4; rr++)
          G[mi * 16 + lk * 4 + rr][wid * 32 + nj * 16 + lr] = acc[mi][nj][rr];
    __syncthreads();

    const float* ig = w_ih + a * 512;
    const float ig0 = ig[j], ig1 = ig[j + 128], ig2 = ig[j + 256], ig3 = ig[j + 384];
    #pragma unroll
    for (int it = 0; it < 4; it++) {
      int r = rb + it * 8;
      float gi = G[r][j]       + ig0 + bs0;
      float gf = G[r][j + 128] + ig1 + bs1;
      float gg = G[r][j + 256] + ig2 + bs2;
      float go = G[r][j + 384] + ig3 + bs3;
      float c = cst[r][j];
      float cn = fsigm(gf) * c + fsigm(gi) * ftanh(gg);
      float h = fsigm(go) * ftanh(cn);
      cst[r][j] = cn;
      unsigned short hb = f2b(h);
      hst[r][j] = hb;
      h_all[((size_t)(r0 + r) * 16 + a) * 128 + j] = hb;
    }
    __syncthreads();
  }
}

// ---------------- fused head MLPs v5: wave-autonomous + 3-deep weight prefetch ring ----------------
__global__ __launch_bounds__(64, 4) void heads_k(
    const unsigned short* __restrict__ hall,   // [131072][128]
    const unsigned short* __restrict__ w1cat,  // [384][128]
    const unsigned short* __restrict__ w2cat,  // [1217][128]
    const float* __restrict__ zb1, const float* __restrict__ qb1, const float* __restrict__ ab1,
    const float* __restrict__ zb2, const float* __restrict__ qb2, const float* __restrict__ ab2,
    float* __restrict__ oz, float* __restrict__ oq, float* __restrict__ oa) {
  __shared__ unsigned short hp[32][136];  // 272B rows, 16B-aligned b128 reads
  const int lane = threadIdx.x & 63;
  const int lr = lane & 15, lk = lane >> 4;
  const int r0 = blockIdx.x * 32;

  const float* B1a[3] = {zb1, qb1, ab1};
  const float* B2a[3] = {zb2, qb2, ab2};
  float*       OOa[3] = {oz, oq, oa};

  #pragma unroll
  for (int hi = 0; hi < 3; hi++) {
    const int Nh    = (hi == 0) ? 600 : (hi == 1) ? 601 : 16;
    const int so    = (hi == 0) ? 0 : (hi == 1) ? 600 : 1201;
    const int NFULL = Nh >> 4;
    const int TAIL  = Nh & 15;
    const int NFT   = NFULL + (TAIL ? 1 : 0);
    const float* b1 = B1a[hi];
    const float* b2 = B2a[hi];
    float* Oh = OOa[hi];

    // ---- hidden: D[hidcol][batchrow] via mfma(w1_frag, hall_frag); 2-stage w1 ring ----
    {
      bf16x8 av[2][4];
      #pragma unroll
      for (int jf = 0; jf < 2; jf++)
        #pragma unroll
        for (int ks = 0; ks < 4; ks++)
          av[jf][ks] = *(const bf16x8*)(hall + (size_t)(r0 + jf * 16 + lr) * 128 + ks * 32 + lk * 8);

      bf16x8 w1buf[2][4];
      #pragma unroll
      for (int ks = 0; ks < 4; ks++)
        w1buf[0][ks] = *(const bf16x8*)(w1cat + (size_t)(hi * 128 + lr) * 128 + ks * 32 + lk * 8);

      #pragma unroll
      for (int nf = 0; nf < 8; nf++) {
        if (nf < 7) {
          #pragma unroll
          for (int ks = 0; ks < 4; ks++)
            w1buf[(nf + 1) & 1][ks] =
                *(const bf16x8*)(w1cat + (size_t)(hi * 128 + (nf + 1) * 16 + lr) * 128 + ks * 32 + lk * 8);
        }
        f32x4 hacc[2] = {};
        #pragma unroll
        for (int ks = 0; ks < 4; ks++)
          #pragma unroll
          for (int jf = 0; jf < 2; jf++)
            hacc[jf] = __builtin_amdgcn_mfma_f32_16x16x32_bf16(w1buf[nf & 1][ks], av[jf][ks], hacc[jf], 0, 0, 0);
        f32x4 bb = *(const f32x4*)(b1 + nf * 16 + lk * 4);
        #pragma unroll
        for (int jf = 0; jf < 2; jf++) {
          u16x4 h4;
          #pragma unroll
          for (int rr = 0; rr < 4; rr++)
            h4[rr] = f2b(fmaxf(hacc[jf][rr] + bb[rr], 0.f));
          *(u16x4*)&hp[jf * 16 + lr][nf * 16 + lk * 4] = h4;
        }
      }
    }
    asm volatile("s_waitcnt lgkmcnt(0)" ::: "memory");
    __builtin_amdgcn_sched_barrier(0);

    bf16x8 hv[2][4];
    #pragma unroll
    for (int jf = 0; jf < 2; jf++)
      #pragma unroll
      for (int ks = 0; ks < 4; ks++)
        hv[jf][ks] = *(const bf16x8*)&hp[jf * 16 + lr][ks * 32 + lk * 8];

    // ---- output: 3-stage named-buffer prefetch ring over w2 frags ----
    bf16x8 W0[4], W1[4], W2[4];
    auto LOADW = [&](bf16x8 (&buf)[4], int f) {
      int rowb = min(f * 16 + lr, Nh - 1);
      #pragma unroll
      for (int ks = 0; ks < 4; ks++)
        buf[ks] = *(const bf16x8*)(w2cat + (size_t)(so + rowb) * 128 + ks * 32 + lk * 8);
    };
    auto STEP = [&](bf16x8 (&buf)[4], int f, bool pre) {
      f32x4 oacc[2] = {};
      #pragma unroll
      for (int ks = 0; ks < 4; ks++)
        #pragma unroll
        for (int jf = 0; jf < 2; jf++)
          oacc[jf] = __builtin_amdgcn_mfma_f32_16x16x32_bf16(buf[ks], hv[jf][ks], oacc[jf], 0, 0, 0);
      if (pre) LOADW(buf, f + 3);
      if (f < NFULL) {
        f32x4 bb = *(const f32x4*)(b2 + f * 16 + lk * 4);
        #pragma unroll
        for (int jf = 0; jf < 2; jf++) {
          f32x4 v = oacc[jf] + bb;
          float* p = Oh + (size_t)(r0 + jf * 16 + lr) * Nh + f * 16 + lk * 4;
          __builtin_memcpy(p, &v, 16);  // dword-aligned dwordx4
        }
      } else {
        #pragma unroll
        for (int jf = 0; jf < 2; jf++)
          #pragma unroll
          for (int rr = 0; rr < 4; rr++) {
            int col = f * 16 + lk * 4 + rr;
            if (col < Nh)
              Oh[(size_t)(r0 + jf * 16 + lr) * Nh + col] = oacc[jf][rr] + b2[col];
          }
      }
    };

    LOADW(W0, 0); LOADW(W1, 1); LOADW(W2, 2);
    int f = 0;
    for (; f + 3 <= NFT; f += 3) {
      STEP(W0, f,     true);
      STEP(W1, f + 1, true);
      STEP(W2, f + 2, true);
    }
    if (f < NFT)     STEP(W0, f,     false);
    if (f + 1 < NFT) STEP(W1, f + 1, false);
  }
}

extern "C" void kernel_launch(void* const* d_in, const int* in_sizes, int n_in,
                              void* d_out, int out_size, void* d_ws, size_t ws_size,
                              hipStream_t stream) {
  const float* obs   = (const float*)d_in[0];
  const float* bb_w1 = (const float*)d_in[1];
  const float* bb_b1 = (const float*)d_in[2];
  const float* bb_w2 = (const float*)d_in[3];
  const float* bb_b2 = (const float*)d_in[4];
  const float* pol_w = (const float*)d_in[5];
  const float* pol_b = (const float*)d_in[6];
  const float* y_w   = (const float*)d_in[7];
  const float* y_b   = (const float*)d_in[8];
  const float* ci_w  = (const float*)d_in[9];
  const float* ci_b  = (const float*)d_in[10];
  const float* w_ih  = (const float*)d_in[11];
  const float* w_hh  = (const float*)d_in[12];
  const float* b_ih  = (const float*)d_in[13];
  const float* b_hh  = (const float*)d_in[14];
  const float* z_w1  = (const float*)d_in[15];
  const float* z_b1  = (const float*)d_in[16];
  const float* z_w2  = (const float*)d_in[17];
  const float* z_b2  = (const float*)d_in[18];
  const float* q_w1  = (const float*)d_in[19];
  const float* q_b1  = (const float*)d_in[20];
  const float* q_w2  = (const float*)d_in[21];
  const float* q_b2  = (const float*)d_in[22];
  const float* a_w1  = (const float*)d_in[23];
  const float* a_b1  = (const float*)d_in[24];
  const float* a_w2  = (const float*)d_in[25];
  const float* a_b2  = (const float*)d_in[26];

  float* out = (float*)d_out;
  float* out_logits = out;                 // [8192][16]
  float* out_y      = out + 131072;        // [8192][600]
  float* out_z      = out + 5046272;       // [131072][600]
  float* out_q      = out + 83689472;      // [131072][601]
  float* out_a      = out + 162463744;     // [131072][16]

  uint8_t* ws = (uint8_t*)d_ws;
  size_t off = 0;
  auto alc = [&](size_t bytes) -> void* {
    void* p = ws + off;
    off = (off + bytes + 255) & ~(size_t)255;
    return p;
  };
  unsigned short* W1T  = (unsigned short*)alc((size_t)512 * 1024 * 2);
  unsigned short* W2T  = (unsigned short*)alc((size_t)512 * 512 * 2);
  unsigned short* polT = (unsigned short*)alc((size_t)16 * 512 * 2);
  unsigned short* yT   = (unsigned short*)alc((size_t)600 * 512 * 2);
  unsigned short* ciT  = (unsigned short*)alc((size_t)128 * 512 * 2);
  unsigned short* whhT = (unsigned short*)alc((size_t)512 * 128 * 2);
  unsigned short* zw1T = (unsigned short*)alc((size_t)128 * 128 * 2);
  unsigned short* qw1T = (unsigned short*)alc((size_t)128 * 128 * 2);
  unsigned short* aw1T = (unsigned short*)alc((size_t)128 * 128 * 2);
  unsigned short* zw2T = (unsigned short*)alc((size_t)600 * 128 * 2);
  unsigned short* qw2T = (unsigned short*)alc((size_t)601 * 128 * 2);
  unsigned short* aw2T = (unsigned short*)alc((size_t)16 * 128 * 2);
  unsigned short* obsb = (unsigned short*)alc((size_t)8192 * 1024 * 2);
  unsigned short* hid1 = (unsigned short*)alc((size_t)8192 * 512 * 2);
  unsigned short* emb  = (unsigned short*)alc((size_t)8192 * 512 * 2);
  float*          c0b  = (float*)alc((size_t)8192 * 128 * 4);
  unsigned short* hall = (unsigned short*)alc((size_t)8192 * 16 * 128 * 2);
  (void)ws_size; (void)in_sizes; (void)n_in; (void)out_size;

  dim3 B256(256);

  TDs td;
  td.d[0]  = {bb_w1, W1T, 1024, 512};
  td.d[1]  = {bb_w2, W2T, 512, 512};
  td.d[2]  = {pol_w, polT, 512, 16};
  td.d[3]  = {y_w,   yT,   512, 600};
  td.d[4]  = {ci_w,  ciT,  512, 128};
  td.d[5]  = {w_hh,  whhT, 128, 512};
  td.d[6]  = {z_w1,  zw1T, 128, 128};
  td.d[7]  = {z_w2,  zw2T, 128, 600};
  td.d[8]  = {q_w1,  qw1T, 128, 128};
  td.d[9]  = {q_w2,  qw2T, 128, 601};
  td.d[10] = {a_w1,  aw1T, 128, 128};
  td.d[11] = {a_w2,  aw2T, 128, 16};
  tconv_all<<<dim3(19, 32, 12), B256, 0, stream>>>(td);

  conv_k<<<dim3(4096), B256, 0, stream>>>(obs, obsb, 8192 * 1024);

  // backbone
  gemm_k<1, true><<<dim3(8, 128), B256, 0, stream>>>(obsb, W1T, bb_b1, hid1, 8192, 512, 1024, 512);
  gemm_k<1, true><<<dim3(8, 128), B256, 0, stream>>>(hid1, W2T, bb_b2, emb,  8192, 512, 512,  512);
  // heads from emb
  gemm_k<0, false><<<dim3(1, 128),  B256, 0, stream>>>(emb, polT, pol_b, out_logits, 8192, 16,  512, 16);
  gemm_k<0, false><<<dim3(10, 128), B256, 0, stream>>>(emb, yT,   y_b,   out_y,      8192, 600, 512, 600);
  gemm_k<0, false><<<dim3(2, 128),  B256, 0, stream>>>(emb, ciT,  ci_b,  c0b,        8192, 128, 512, 128);
  // fused LSTM scan (16 waves/block)
  lstm_k<<<dim3(256), dim3(1024), 0, stream>>>(c0b, whhT, w_ih, b_ih, b_hh, hall);
  // fused head MLPs: one wave per 32 rows, barrier-free, ring-prefetched weights
  heads_k<<<dim3(4096), dim3(64), 0, stream>>>(hall,
                                               zw1T, zw2T,
                                               z_b1, q_b1, a_b1,
                                               z_b2, q_b2, a_b2,
                                               out_z, out_q, out_a);
}

// Round 7
// 488.702 us; speedup vs baseline: 1.0654x; 1.0654x over previous
//
#include <hip/hip_runtime.h>
#include <stdint.h>

typedef short bf16x8 __attribute__((ext_vector_type(8)));
typedef float f32x4 __attribute__((ext_vector_type(4)));
typedef unsigned short u16x4 __attribute__((ext_vector_type(4)));

__device__ __forceinline__ unsigned short f2b(float f) {
  union { float f; unsigned u; } v; v.f = f;
  unsigned r = v.u + 0x7fffu + ((v.u >> 16) & 1u);
  return (unsigned short)(r >> 16);
}
__device__ __forceinline__ float fsigm(float x) { return 1.f / (1.f + __expf(-x)); }
__device__ __forceinline__ float ftanh(float x) {
  float t = __expf(-2.f * fabsf(x));
  float r = (1.f - t) / (1.f + t);
  return copysignf(r, x);
}

// ---------------- fused transpose+convert: f32[R][C] -> bf16 out[C][R], 12 matrices ----------------
struct TD { const float* in; unsigned short* out; int R, C; };
struct TDs { TD d[12]; };

__global__ __launch_bounds__(256) void tconv_all(TDs ds) {
  TD t = ds.d[blockIdx.z];
  int c0 = blockIdx.x * 32, r0 = blockIdx.y * 32;
  if (c0 >= t.C || r0 >= t.R) return;
  __shared__ float tl[32][33];
  int tx = threadIdx.x & 31, ty = threadIdx.x >> 5;  // 32 x 8
  #pragma unroll
  for (int i = 0; i < 32; i += 8) {
    int r = r0 + ty + i, c = c0 + tx;
    tl[ty + i][tx] = (r < t.R && c < t.C) ? t.in[(size_t)r * t.C + c] : 0.f;
  }
  __syncthreads();
  #pragma unroll
  for (int i = 0; i < 32; i += 8) {
    int c = c0 + ty + i, r = r0 + tx;
    if (c < t.C && r < t.R) t.out[(size_t)c * t.R + r] = f2b(tl[tx][ty + i]);
  }
}

// ---------------- f32 -> bf16 flat convert ----------------
__global__ __launch_bounds__(256) void conv_k(const float* __restrict__ in,
                                              unsigned short* __restrict__ out, int n) {
  int i = (blockIdx.x * 256 + threadIdx.x) * 8;
  if (i >= n) return;
  float4 a = *(const float4*)(in + i);
  float4 b = *(const float4*)(in + i + 4);
  bf16x8 v;
  v[0] = (short)f2b(a.x); v[1] = (short)f2b(a.y); v[2] = (short)f2b(a.z); v[3] = (short)f2b(a.w);
  v[4] = (short)f2b(b.x); v[5] = (short)f2b(b.y); v[6] = (short)f2b(b.z); v[7] = (short)f2b(b.w);
  *(bf16x8*)(out + i) = v;
}

// ---------------- generic MFMA GEMM: C = act(A[M,K] @ BT[N,K]^T + bias) ----------------
template <int ACT, bool OBF16>
__global__ __launch_bounds__(256) void gemm_k(const unsigned short* __restrict__ A,
                                              const unsigned short* __restrict__ BT,
                                              const float* __restrict__ bias,
                                              void* __restrict__ Cp,
                                              int M, int N, int K, int ldC) {
  __shared__ unsigned short As[64][40];
  __shared__ unsigned short Bs[64][40];
  const int tid = threadIdx.x;
  const int n0 = blockIdx.x * 64;
  const int m0 = blockIdx.y * 64;
  const int wid = tid >> 6, lane = tid & 63;
  const int wm = (wid >> 1) * 32, wn = (wid & 1) * 32;
  const int lr = lane & 15, lk = lane >> 4;
  const int sr = tid >> 2, sc = (tid & 3) * 8;

  f32x4 acc[2][2] = {};

  for (int k0 = 0; k0 < K; k0 += 32) {
    *(bf16x8*)&As[sr][sc] = *(const bf16x8*)(A + (size_t)(m0 + sr) * K + k0 + sc);
    {
      int n = n0 + sr;
      bf16x8 v = {};
      if (n < N) v = *(const bf16x8*)(BT + (size_t)n * K + k0 + sc);
      *(bf16x8*)&Bs[sr][sc] = v;
    }
    __syncthreads();
    bf16x8 af[2], bfr[2];
    #pragma unroll
    for (int mi = 0; mi < 2; mi++) af[mi] = *(const bf16x8*)&As[wm + mi * 16 + lr][lk * 8];
    #pragma unroll
    for (int ni = 0; ni < 2; ni++) bfr[ni] = *(const bf16x8*)&Bs[wn + ni * 16 + lr][lk * 8];
    #pragma unroll
    for (int mi = 0; mi < 2; mi++)
      #pragma unroll
      for (int ni = 0; ni < 2; ni++)
        acc[mi][ni] = __builtin_amdgcn_mfma_f32_16x16x32_bf16(af[mi], bfr[ni], acc[mi][ni], 0, 0, 0);
    __syncthreads();
  }

  #pragma unroll
  for (int mi = 0; mi < 2; mi++)
    #pragma unroll
    for (int ni = 0; ni < 2; ni++) {
      int col = n0 + wn + ni * 16 + lr;
      if (col >= N) continue;
      float bv = bias[col];
      #pragma unroll
      for (int r = 0; r < 4; r++) {
        int row = m0 + wm + mi * 16 + lk * 4 + r;
        float v = acc[mi][ni][r] + bv;
        if (ACT == 1) v = fmaxf(v, 0.f);
        if (OBF16) ((unsigned short*)Cp)[(size_t)row * ldC + col] = f2b(v);
        else       ((float*)Cp)[(size_t)row * ldC + col] = v;
      }
    }
}

// ---------------- fused LSTM scan over 16 steps (1024 threads, 16 waves) ----------------
__global__ __launch_bounds__(1024) void lstm_k(const float* __restrict__ c0,
                                               const unsigned short* __restrict__ whhT,  // [512][128]
                                               const float* __restrict__ w_ih,           // [16][512]
                                               const float* __restrict__ b_ih,
                                               const float* __restrict__ b_hh,
                                               unsigned short* __restrict__ h_all) {     // [8192][16][128]
  __shared__ float G[32][516];
  __shared__ float cst[32][128];
  __shared__ unsigned short hst[32][136];
  const int tid = threadIdx.x, lane = tid & 63, wid = tid >> 6;  // wid 0..15
  const int r0 = blockIdx.x * 32;
  const int lr = lane & 15, lk = lane >> 4;

  bf16x8 wv[2][4];
  #pragma unroll
  for (int nj = 0; nj < 2; nj++)
    #pragma unroll
    for (int ks = 0; ks < 4; ks++)
      wv[nj][ks] = *(const bf16x8*)(whhT + (size_t)(wid * 32 + nj * 16 + lr) * 128 + ks * 32 + lk * 8);

  const int j = tid & 127;
  const int rb = tid >> 7;  // 0..7
  const float bs0 = b_ih[j]       + b_hh[j];
  const float bs1 = b_ih[j + 128] + b_hh[j + 128];
  const float bs2 = b_ih[j + 256] + b_hh[j + 256];
  const float bs3 = b_ih[j + 384] + b_hh[j + 384];

  {
    int r = tid >> 5, j4 = (tid & 31) * 4;
    float4 c4 = *(const float4*)(c0 + (size_t)(r0 + r) * 128 + j4);
    *(f32x4*)&cst[r][j4] = f32x4{c4.x, c4.y, c4.z, c4.w};
    u16x4 h4;
    h4[0] = f2b(ftanh(c4.x)); h4[1] = f2b(ftanh(c4.y));
    h4[2] = f2b(ftanh(c4.z)); h4[3] = f2b(ftanh(c4.w));
    *(u16x4*)&hst[r][j4] = h4;
  }
  __syncthreads();

  for (int a = 0; a < 16; a++) {
    f32x4 acc[2][2] = {};
    #pragma unroll
    for (int ks = 0; ks < 4; ks++) {
      bf16x8 af0 = *(const bf16x8*)&hst[lr][ks * 32 + lk * 8];
      bf16x8 af1 = *(const bf16x8*)&hst[16 + lr][ks * 32 + lk * 8];
      #pragma unroll
      for (int nj = 0; nj < 2; nj++) {
        acc[0][nj] = __builtin_amdgcn_mfma_f32_16x16x32_bf16(af0, wv[nj][ks], acc[0][nj], 0, 0, 0);
        acc[1][nj] = __builtin_amdgcn_mfma_f32_16x16x32_bf16(af1, wv[nj][ks], acc[1][nj], 0, 0, 0);
      }
    }
    #pragma unroll
    for (int mi = 0; mi < 2; mi++)
      #pragma unroll
      for (int nj = 0; nj < 2; nj++)
        #pragma unroll
        for (int rr = 0; rr < 4; rr++)
          G[mi * 16 + lk * 4 + rr][wid * 32 + nj * 16 + lr] = acc[mi][nj][rr];
    __syncthreads();

    const float* ig = w_ih + a * 512;
    const float ig0 = ig[j], ig1 = ig[j + 128], ig2 = ig[j + 256], ig3 = ig[j + 384];
    #pragma unroll
    for (int it = 0; it < 4; it++) {
      int r = rb + it * 8;
      float gi = G[r][j]       + ig0 + bs0;
      float gf = G[r][j + 128] + ig1 + bs1;
      float gg = G[r][j + 256] + ig2 + bs2;
      float go = G[r][j + 384] + ig3 + bs3;
      float c = cst[r][j];
      float cn = fsigm(gf) * c + fsigm(gi) * ftanh(gg);
      float h = fsigm(go) * ftanh(cn);
      cst[r][j] = cn;
      unsigned short hb = f2b(h);
      hst[r][j] = hb;
      h_all[((size_t)(r0 + r) * 16 + a) * 128 + j] = hb;
    }
    __syncthreads();
  }
}

// ---------------- hidden_k: hall -> hh_z, hh_q (bf16) + full aux head ----------------
// Wave-autonomous (32 rows/wave, 4 waves/block). Swapped-operand MFMA:
// D col = batchrow (lane&15), D row = out-col ((lane>>4)*4+reg).
__global__ __launch_bounds__(256, 4) void hidden_k(
    const unsigned short* __restrict__ hall,   // [131072][128]
    const unsigned short* __restrict__ w1cat,  // [384][128]  z|q|a
    const unsigned short* __restrict__ w2a,    // [16][128]   aux out weights
    const float* __restrict__ zb1, const float* __restrict__ qb1, const float* __restrict__ ab1,
    const float* __restrict__ ab2,
    unsigned short* __restrict__ hhz, unsigned short* __restrict__ hhq,
    float* __restrict__ oa) {
  __shared__ float bls[384];
  __shared__ unsigned short hp[4][32][136];
  const int tid = threadIdx.x, lane = tid & 63, wid = tid >> 6;
  const int lr = lane & 15, lk = lane >> 4;
  const int r0 = blockIdx.x * 128 + wid * 32;

  if (tid < 128) { bls[tid] = zb1[tid]; bls[256 + tid] = ab1[tid]; }
  else if (tid < 256) bls[tid] = qb1[tid - 128];
  __syncthreads();

  bf16x8 av[2][4];
  #pragma unroll
  for (int jf = 0; jf < 2; jf++)
    #pragma unroll
    for (int ks = 0; ks < 4; ks++)
      av[jf][ks] = *(const bf16x8*)(hall + (size_t)(r0 + jf * 16 + lr) * 128 + ks * 32 + lk * 8);

  #pragma unroll
  for (int hi = 0; hi < 3; hi++) {
    unsigned short* hh = (hi == 0) ? hhz : hhq;
    #pragma unroll
    for (int nf = 0; nf < 8; nf++) {
      bf16x8 w1v[4];
      #pragma unroll
      for (int ks = 0; ks < 4; ks++)
        w1v[ks] = *(const bf16x8*)(w1cat + (size_t)(hi * 128 + nf * 16 + lr) * 128 + ks * 32 + lk * 8);
      f32x4 hacc[2] = {};
      #pragma unroll
      for (int ks = 0; ks < 4; ks++)
        #pragma unroll
        for (int jf = 0; jf < 2; jf++)
          hacc[jf] = __builtin_amdgcn_mfma_f32_16x16x32_bf16(w1v[ks], av[jf][ks], hacc[jf], 0, 0, 0);
      f32x4 bb = *(const f32x4*)&bls[hi * 128 + nf * 16 + lk * 4];
      #pragma unroll
      for (int jf = 0; jf < 2; jf++) {
        u16x4 h4;
        #pragma unroll
        for (int rr = 0; rr < 4; rr++)
          h4[rr] = f2b(fmaxf(hacc[jf][rr] + bb[rr], 0.f));
        if (hi < 2)
          *(u16x4*)(hh + (size_t)(r0 + jf * 16 + lr) * 128 + nf * 16 + lk * 4) = h4;
        else
          *(u16x4*)&hp[wid][jf * 16 + lr][nf * 16 + lk * 4] = h4;
      }
    }
  }

  asm volatile("s_waitcnt lgkmcnt(0)" ::: "memory");
  __builtin_amdgcn_sched_barrier(0);

  // aux output: 16 cols
  bf16x8 hv[2][4];
  #pragma unroll
  for (int jf = 0; jf < 2; jf++)
    #pragma unroll
    for (int ks = 0; ks < 4; ks++)
      hv[jf][ks] = *(const bf16x8*)&hp[wid][jf * 16 + lr][ks * 32 + lk * 8];
  bf16x8 wa[4];
  #pragma unroll
  for (int ks = 0; ks < 4; ks++)
    wa[ks] = *(const bf16x8*)(w2a + (size_t)lr * 128 + ks * 32 + lk * 8);
  f32x4 oacc[2] = {};
  #pragma unroll
  for (int ks = 0; ks < 4; ks++)
    #pragma unroll
    for (int jf = 0; jf < 2; jf++)
      oacc[jf] = __builtin_amdgcn_mfma_f32_16x16x32_bf16(wa[ks], hv[jf][ks], oacc[jf], 0, 0, 0);
  f32x4 bbo = *(const f32x4*)(ab2 + lk * 4);
  #pragma unroll
  for (int jf = 0; jf < 2; jf++) {
    f32x4 v = oacc[jf] + bbo;
    *(f32x4*)(oa + (size_t)(r0 + jf * 16 + lr) * 16 + lk * 4) = v;
  }
}

// ---------------- out_k: store-decoupled output GEMM, w2 slice LDS-resident ----------------
// Block: 4 waves x 64 rows = 256 rows, col slice = 13 frags (208 cols) in LDS (swizzled).
// Inner loop: ds_read -> MFMA -> store only. NO global loads => stores never waited on.
template <int NH>
__global__ __launch_bounds__(256, 2) void out_k(
    const unsigned short* __restrict__ hh,  // [131072][128]
    const unsigned short* __restrict__ w2,  // [NH][128]
    const float* __restrict__ b2,
    float* __restrict__ O) {
  __shared__ unsigned short wls[208 * 128];  // 53 KB, row-major 256B rows, slot-XOR-swizzled
  __shared__ float bls[208];
  const int tid = threadIdx.x, lane = tid & 63, wid = tid >> 6;
  const int lr = lane & 15, lk = lane >> 4;
  const int r0 = blockIdx.x * 256 + wid * 64;
  const int gf0 = blockIdx.y * 13;

  // stage w2 slice: LDS[row][slot] = global slot (slot ^ (row&7))  [2-way-free on read]
  #pragma unroll
  for (int it = 0; it < 13; it++) {
    int row = it * 16 + (tid >> 4);
    int slot = tid & 15;
    int gr = gf0 * 16 + row; if (gr > NH - 1) gr = NH - 1;
    bf16x8 v = *(const bf16x8*)(w2 + (size_t)gr * 128 + ((slot ^ (row & 7)) << 3));
    *(bf16x8*)&wls[row * 128 + slot * 8] = v;
  }
  if (tid < 52) {
    int col = gf0 * 16 + tid * 4;
    f32x4 b = {};
    #pragma unroll
    for (int r = 0; r < 4; r++) b[r] = (col + r < NH) ? b2[col + r] : 0.f;
    *(f32x4*)&bls[tid * 4] = b;
  }

  // A rows into registers (only global loads; all before the loop)
  bf16x8 av[4][4];
  #pragma unroll
  for (int mi = 0; mi < 4; mi++)
    #pragma unroll
    for (int ks = 0; ks < 4; ks++)
      av[mi][ks] = *(const bf16x8*)(hh + (size_t)(r0 + mi * 16 + lr) * 128 + ks * 32 + lk * 8);
  __syncthreads();

  for (int f = 0; f < 13; f++) {
    int wrow = f * 16 + lr;
    bf16x8 wv[4];
    #pragma unroll
    for (int ks = 0; ks < 4; ks++) {
      int sl = (ks * 4 + lk) ^ (wrow & 7);
      wv[ks] = *(const bf16x8*)&wls[wrow * 128 + sl * 8];
    }
    f32x4 oacc[4] = {};
    #pragma unroll
    for (int ks = 0; ks < 4; ks++)
      #pragma unroll
      for (int mi = 0; mi < 4; mi++)
        oacc[mi] = __builtin_amdgcn_mfma_f32_16x16x32_bf16(wv[ks], av[mi][ks], oacc[mi], 0, 0, 0);
    f32x4 bb = *(const f32x4*)&bls[f * 16 + lk * 4];
    int col = (gf0 + f) * 16 + lk * 4;
    if (col + 3 < NH) {
      #pragma unroll
      for (int mi = 0; mi < 4; mi++) {
        f32x4 v = oacc[mi] + bb;
        float* p = O + (size_t)(r0 + mi * 16 + lr) * NH + col;
        if (NH % 4 == 0) *(f32x4*)p = v;           // z rows are 16B-aligned
        else __builtin_memcpy(p, &v, 16);           // q rows only 4B-aligned
      }
    } else if (col < NH) {
      #pragma unroll
      for (int mi = 0; mi < 4; mi++)
        #pragma unroll
        for (int rr = 0; rr < 4; rr++)
          if (col + rr < NH)
            O[(size_t)(r0 + mi * 16 + lr) * NH + col + rr] = oacc[mi][rr] + bb[rr];
    }
  }
}

extern "C" void kernel_launch(void* const* d_in, const int* in_sizes, int n_in,
                              void* d_out, int out_size, void* d_ws, size_t ws_size,
                              hipStream_t stream) {
  const float* obs   = (const float*)d_in[0];
  const float* bb_w1 = (const float*)d_in[1];
  const float* bb_b1 = (const float*)d_in[2];
  const float* bb_w2 = (const float*)d_in[3];
  const float* bb_b2 = (const float*)d_in[4];
  const float* pol_w = (const float*)d_in[5];
  const float* pol_b = (const float*)d_in[6];
  const float* y_w   = (const float*)d_in[7];
  const float* y_b   = (const float*)d_in[8];
  const float* ci_w  = (const float*)d_in[9];
  const float* ci_b  = (const float*)d_in[10];
  const float* w_ih  = (const float*)d_in[11];
  const float* w_hh  = (const float*)d_in[12];
  const float* b_ih  = (const float*)d_in[13];
  const float* b_hh  = (const float*)d_in[14];
  const float* z_w1  = (const float*)d_in[15];
  const float* z_b1  = (const float*)d_in[16];
  const float* z_w2  = (const float*)d_in[17];
  const float* z_b2  = (const float*)d_in[18];
  const float* q_w1  = (const float*)d_in[19];
  const float* q_b1  = (const float*)d_in[20];
  const float* q_w2  = (const float*)d_in[21];
  const float* q_b2  = (const float*)d_in[22];
  const float* a_w1  = (const float*)d_in[23];
  const float* a_b1  = (const float*)d_in[24];
  const float* a_w2  = (const float*)d_in[25];
  const float* a_b2  = (const float*)d_in[26];

  float* out = (float*)d_out;
  float* out_logits = out;                 // [8192][16]
  float* out_y      = out + 131072;        // [8192][600]
  float* out_z      = out + 5046272;       // [131072][600]
  float* out_q      = out + 83689472;      // [131072][601]
  float* out_a      = out + 162463744;     // [131072][16]

  uint8_t* ws = (uint8_t*)d_ws;
  size_t off = 0;
  auto alc = [&](size_t bytes) -> void* {
    void* p = ws + off;
    off = (off + bytes + 255) & ~(size_t)255;
    return p;
  };
  unsigned short* W1T  = (unsigned short*)alc((size_t)512 * 1024 * 2);
  unsigned short* W2T  = (unsigned short*)alc((size_t)512 * 512 * 2);
  unsigned short* polT = (unsigned short*)alc((size_t)16 * 512 * 2);
  unsigned short* yT   = (unsigned short*)alc((size_t)600 * 512 * 2);
  unsigned short* ciT  = (unsigned short*)alc((size_t)128 * 512 * 2);
  unsigned short* whhT = (unsigned short*)alc((size_t)512 * 128 * 2);
  // w1cat: z|q|a hidden weights contiguous
  unsigned short* zw1T = (unsigned short*)alc((size_t)128 * 128 * 2);
  unsigned short* qw1T = (unsigned short*)alc((size_t)128 * 128 * 2);
  unsigned short* aw1T = (unsigned short*)alc((size_t)128 * 128 * 2);
  // w2cat: z|q|a output weights contiguous (sizes are 256-multiples)
  unsigned short* zw2T = (unsigned short*)alc((size_t)600 * 128 * 2);
  unsigned short* qw2T = (unsigned short*)alc((size_t)601 * 128 * 2);
  unsigned short* aw2T = (unsigned short*)alc((size_t)16 * 128 * 2);
  unsigned short* obsb = (unsigned short*)alc((size_t)8192 * 1024 * 2);  // 16.78 MB
  unsigned short* hid1 = (unsigned short*)alc((size_t)8192 * 512 * 2);   // 8.39 MB
  unsigned short* emb  = (unsigned short*)alc((size_t)8192 * 512 * 2);   // 8.39 MB
  float*          c0b  = (float*)alc((size_t)8192 * 128 * 4);
  unsigned short* hall = (unsigned short*)alc((size_t)8192 * 16 * 128 * 2);
  // hh_z reuses obsb+hid1+emb (33.55 MB, dead by hidden_k); hh_q fresh
  unsigned short* hhz  = obsb;
  unsigned short* hhq  = (unsigned short*)alc((size_t)131072 * 128 * 2);
  (void)ws_size; (void)in_sizes; (void)n_in; (void)out_size;

  dim3 B256(256);

  TDs td;
  td.d[0]  = {bb_w1, W1T, 1024, 512};
  td.d[1]  = {bb_w2, W2T, 512, 512};
  td.d[2]  = {pol_w, polT, 512, 16};
  td.d[3]  = {y_w,   yT,   512, 600};
  td.d[4]  = {ci_w,  ciT,  512, 128};
  td.d[5]  = {w_hh,  whhT, 128, 512};
  td.d[6]  = {z_w1,  zw1T, 128, 128};
  td.d[7]  = {z_w2,  zw2T, 128, 600};
  td.d[8]  = {q_w1,  qw1T, 128, 128};
  td.d[9]  = {q_w2,  qw2T, 128, 601};
  td.d[10] = {a_w1,  aw1T, 128, 128};
  td.d[11] = {a_w2,  aw2T, 128, 16};
  tconv_all<<<dim3(19, 32, 12), B256, 0, stream>>>(td);

  conv_k<<<dim3(4096), B256, 0, stream>>>(obs, obsb, 8192 * 1024);

  // backbone
  gemm_k<1, true><<<dim3(8, 128), B256, 0, stream>>>(obsb, W1T, bb_b1, hid1, 8192, 512, 1024, 512);
  gemm_k<1, true><<<dim3(8, 128), B256, 0, stream>>>(hid1, W2T, bb_b2, emb,  8192, 512, 512,  512);
  // heads from emb
  gemm_k<0, false><<<dim3(1, 128),  B256, 0, stream>>>(emb, polT, pol_b, out_logits, 8192, 16,  512, 16);
  gemm_k<0, false><<<dim3(10, 128), B256, 0, stream>>>(emb, yT,   y_b,   out_y,      8192, 600, 512, 600);
  gemm_k<0, false><<<dim3(2, 128),  B256, 0, stream>>>(emb, ciT,  ci_b,  c0b,        8192, 128, 512, 128);
  // fused LSTM scan (16 waves/block)
  lstm_k<<<dim3(256), dim3(1024), 0, stream>>>(c0b, whhT, w_ih, b_ih, b_hh, hall);
  // heads: hidden (+aux head fully), then store-decoupled output GEMMs
  hidden_k<<<dim3(1024), B256, 0, stream>>>(hall, zw1T, aw2T,
                                            z_b1, q_b1, a_b1, a_b2,
                                            hhz, hhq, out_a);
  out_k<600><<<dim3(512, 3), B256, 0, stream>>>(hhz, zw2T, z_b2, out_z);
  out_k<601><<<dim3(512, 3), B256, 0, stream>>>(hhq, qw2T, q_b2, out_q);
}